// Round 1
// baseline (214.973 us; speedup 1.0000x reference)
//
#include <hip/hip_runtime.h>

#define N_ROWS 16384
#define C_COLS 2048
#define TWO_C 4096            // sums(2048) + sqsums(2048) per view
#define N_VIEWS 6
#define MOMENT_F 1.6384f      // N/10000
#define SEGS 128              // row segments for K1 parallelism
#define NCHUNK 8              // segment chunks for K1b parallelism
#define SEG_PER_CHUNK (SEGS / NCHUNK)

// ws layout (main path, NO zero-init required — every slot written exactly once):
//   byte 0      : partCnt [SEGS*V]        per-(seg,view) matched-row count
//   byte 4096   : cnt2    [NCHUNK*V]      chunk-reduced counts (written by k1b blk 0)
//   byte 8192   : part    [SEGS*V*TWO_C]  per-(seg,view) sum/sq slabs (12.6 MB)
//   after part  : acc2    [NCHUNK*V*TWO_C] chunk-reduced slabs (786 KB)

// ---------------------------------------------------------------------------
// K1: grid = V*SEGS blocks, 256 thr. Compact matching rows into LDS, stream
// rows with float4 loads (4x unrolled -> 8 loads in flight), write per-block
// partial slab with plain coalesced stores. NO global atomics.
// ---------------------------------------------------------------------------
__global__ __launch_bounds__(256) void k1_segstats(
    const float* __restrict__ x, const int* __restrict__ views,
    float* __restrict__ part, float* __restrict__ partCnt, int L) {
  const int s = blockIdx.x / N_VIEWS;
  const int v = blockIdx.x % N_VIEWS;
  const int r0 = s * L;
  const int len = min(L, N_ROWS - r0);

  __shared__ int lds_list[256];
  __shared__ int lds_cnt;
  if (threadIdx.x == 0) lds_cnt = 0;
  __syncthreads();
  for (int i = threadIdx.x; i < len; i += 256) {
    if (views[r0 + i] == v) {
      int p = atomicAdd(&lds_cnt, 1);
      lds_list[p] = r0 + i;
    }
  }
  __syncthreads();
  const int m = lds_cnt;
  const int t = threadIdx.x;

  float4 sA = {0.f,0.f,0.f,0.f}, sB = {0.f,0.f,0.f,0.f};
  float4 qA = {0.f,0.f,0.f,0.f}, qB = {0.f,0.f,0.f,0.f};

  int j = 0;
  for (; j + 4 <= m; j += 4) {
    int r0_ = lds_list[j], r1_ = lds_list[j+1];
    int r2_ = lds_list[j+2], r3_ = lds_list[j+3];
    const float4* p0 = (const float4*)(x + (size_t)r0_ * C_COLS);
    const float4* p1 = (const float4*)(x + (size_t)r1_ * C_COLS);
    const float4* p2 = (const float4*)(x + (size_t)r2_ * C_COLS);
    const float4* p3 = (const float4*)(x + (size_t)r3_ * C_COLS);
    float4 a0 = p0[t], b0 = p0[t+256];
    float4 a1 = p1[t], b1 = p1[t+256];
    float4 a2 = p2[t], b2 = p2[t+256];
    float4 a3 = p3[t], b3 = p3[t+256];
#define ACC(a,b) \
    sA.x += a.x; sA.y += a.y; sA.z += a.z; sA.w += a.w; \
    sB.x += b.x; sB.y += b.y; sB.z += b.z; sB.w += b.w; \
    qA.x = fmaf(a.x,a.x,qA.x); qA.y = fmaf(a.y,a.y,qA.y); \
    qA.z = fmaf(a.z,a.z,qA.z); qA.w = fmaf(a.w,a.w,qA.w); \
    qB.x = fmaf(b.x,b.x,qB.x); qB.y = fmaf(b.y,b.y,qB.y); \
    qB.z = fmaf(b.z,b.z,qB.z); qB.w = fmaf(b.w,b.w,qB.w);
    ACC(a0,b0) ACC(a1,b1) ACC(a2,b2) ACC(a3,b3)
  }
  for (; j < m; ++j) {
    int r = lds_list[j];
    const float4* p = (const float4*)(x + (size_t)r * C_COLS);
    float4 a = p[t], b = p[t+256];
    ACC(a,b)
  }
#undef ACC

  float4* slab = (float4*)(part + (size_t)(s * N_VIEWS + v) * TWO_C);
  slab[t]       = sA;   // sum, cols 4t..4t+3
  slab[t + 256] = sB;   // sum, cols 1024+4t..
  slab[t + 512] = qA;   // sq,  cols 4t..
  slab[t + 768] = qB;   // sq,  cols 1024+4t..
  if (t == 0) partCnt[s * N_VIEWS + v] = (float)m;
}

// ---------------------------------------------------------------------------
// K1b: reduce partials over segments into per-chunk slabs. Grid = 192 blocks.
// Thread (chunk, v, c4) sums SEG_PER_CHUNK float4 partials, plain store into
// acc2 (each element written exactly once -> no zero-init, no atomics).
// Block 0 additionally chunk-reduces the 768 partCnt values into cnt2[48].
// ---------------------------------------------------------------------------
__global__ __launch_bounds__(256) void k1b_reduce(
    const float4* __restrict__ part4, float4* __restrict__ acc2_4,
    const float* __restrict__ partCnt, float* __restrict__ cnt2) {
  const int u = blockIdx.x * 256 + threadIdx.x;
  const int chunk = u / (N_VIEWS * 1024);
  const int o = u % (N_VIEWS * 1024);
  const int v = o >> 10;
  const int c4 = o & 1023;
  float4 s = {0.f, 0.f, 0.f, 0.f};
  const int segBase = chunk * SEG_PER_CHUNK;
#pragma unroll
  for (int i = 0; i < SEG_PER_CHUNK; ++i) {
    float4 p = part4[(size_t)((segBase + i) * N_VIEWS + v) * 1024 + c4];
    s.x += p.x; s.y += p.y; s.z += p.z; s.w += p.w;
  }
  acc2_4[(size_t)(chunk * N_VIEWS + v) * 1024 + c4] = s;

  if (blockIdx.x == 0 && threadIdx.x < NCHUNK * N_VIEWS) {
    const int ch = threadIdx.x / N_VIEWS;
    const int vv = threadIdx.x % N_VIEWS;
    float cs = 0.f;
#pragma unroll
    for (int i = 0; i < SEG_PER_CHUNK; ++i)
      cs += partCnt[(ch * SEG_PER_CHUNK + i) * N_VIEWS + vv];
    cnt2[threadIdx.x] = cs;
  }
}

// ---------------------------------------------------------------------------
// K2: single block, 1024 thr, 2 cols/thread. Sums the 8 chunk slabs (786 KB),
// finishes means/stds/new-centers/loss, writes out[0] with a plain store
// (and zero-fills any extra out elements). No memset, no atomics.
// ---------------------------------------------------------------------------
__global__ __launch_bounds__(1024) void k2_finish(
    const float* __restrict__ acc2, const float* __restrict__ cnt2,
    const float* __restrict__ cmean, const float* __restrict__ cstd,
    float* __restrict__ out, int out_elems) {
  __shared__ float scnt[N_VIEWS];
  __shared__ float wsum[16];
  if (threadIdx.x < N_VIEWS) {
    float s = 0.f;
#pragma unroll
    for (int k = 0; k < NCHUNK; ++k) s += cnt2[k * N_VIEWS + threadIdx.x];
    scnt[threadIdx.x] = s;
  }
  __syncthreads();

  float cnt[N_VIEWS];
  float nvalid = 0.f;
#pragma unroll
  for (int v = 0; v < N_VIEWS; ++v) {
    cnt[v] = scnt[v];
    nvalid += (cnt[v] > 1.5f) ? 1.f : 0.f;
  }

  float total = 0.f;
#pragma unroll
  for (int half = 0; half < 2; ++half) {
    const int c = threadIdx.x + half * 1024;
    float mean[N_VIEWS], sd[N_VIEWS];
    float nm = 0.f, ns = 0.f;
#pragma unroll
    for (int v = 0; v < N_VIEWS; ++v) {
      float su = 0.f, sq = 0.f;
#pragma unroll
      for (int k = 0; k < NCHUNK; ++k) {
        const float* base = acc2 + (size_t)(k * N_VIEWS + v) * TWO_C;
        su += base[c];
        sq += base[2048 + c];
      }
      float n = fmaxf(cnt[v], 1.f);
      float mu = su / n;
      float var = (sq - cnt[v] * mu * mu) / fmaxf(cnt[v] - 1.f, 1.f);
      float sdv = sqrtf(fmaxf(var, 0.f));
      mean[v] = mu;
      sd[v] = sdv;
      if (cnt[v] > 1.5f) { nm += mu; ns += sdv; }
    }
    nm /= nvalid;
    ns /= nvalid;
    const float cm = cmean[c] * (1.f - MOMENT_F) + nm * MOMENT_F;
    const float cs = cstd[c]  * (1.f - MOMENT_F) + ns * MOMENT_F;
#pragma unroll
    for (int v = 0; v < N_VIEWS; ++v) {
      if (cnt[v] > 1.5f) {
        float d1 = mean[v] - cm;
        float d2 = sd[v] - cs;
        total = fmaf(d1, d1, total);
        total = fmaf(d2, d2, total);
      }
    }
  }
  total /= (2.f * nvalid);

  for (int o = 32; o > 0; o >>= 1) total += __shfl_down(total, o, 64);
  const int lane = threadIdx.x & 63;
  const int w = threadIdx.x >> 6;
  if (lane == 0) wsum[w] = total;
  __syncthreads();
  if (threadIdx.x == 0) {
    float t = 0.f;
#pragma unroll
    for (int i = 0; i < 16; ++i) t += wsum[i];
    out[0] = t;
  }
  // zero any extra output elements (harness may poison out)
  for (int i = threadIdx.x + 1; i < out_elems; i += 1024) out[i] = 0.f;
}

// ---------------------------------------------------------------------------
// Fallback path (ws too small): contended-atomic accumulation + memsets.
// ---------------------------------------------------------------------------
__global__ __launch_bounds__(256) void k1_segstats_atomic(
    const float* __restrict__ x, const int* __restrict__ views,
    float* __restrict__ acc, float* __restrict__ counts, int L) {
  const int s = blockIdx.x / N_VIEWS;
  const int v = blockIdx.x % N_VIEWS;
  const int r0 = s * L;
  const int len = min(L, N_ROWS - r0);
  __shared__ int lds_list[256];
  __shared__ int lds_cnt;
  if (threadIdx.x == 0) lds_cnt = 0;
  __syncthreads();
  for (int i = threadIdx.x; i < len; i += 256)
    if (views[r0 + i] == v) lds_list[atomicAdd(&lds_cnt, 1)] = r0 + i;
  __syncthreads();
  const int m = lds_cnt;
  const int t = threadIdx.x;
  float4 sA = {0,0,0,0}, sB = {0,0,0,0}, qA = {0,0,0,0}, qB = {0,0,0,0};
  for (int j = 0; j < m; ++j) {
    const float4* p = (const float4*)(x + (size_t)lds_list[j] * C_COLS);
    float4 a = p[t], b = p[t+256];
    sA.x += a.x; sA.y += a.y; sA.z += a.z; sA.w += a.w;
    sB.x += b.x; sB.y += b.y; sB.z += b.z; sB.w += b.w;
    qA.x = fmaf(a.x,a.x,qA.x); qA.y = fmaf(a.y,a.y,qA.y);
    qA.z = fmaf(a.z,a.z,qA.z); qA.w = fmaf(a.w,a.w,qA.w);
    qB.x = fmaf(b.x,b.x,qB.x); qB.y = fmaf(b.y,b.y,qB.y);
    qB.z = fmaf(b.z,b.z,qB.z); qB.w = fmaf(b.w,b.w,qB.w);
  }
  float* base = acc + v * TWO_C;
  const int cA = 4 * t, cB = 1024 + 4 * t;
  atomicAdd(base+cA+0,sA.x); atomicAdd(base+cA+1,sA.y);
  atomicAdd(base+cA+2,sA.z); atomicAdd(base+cA+3,sA.w);
  atomicAdd(base+cB+0,sB.x); atomicAdd(base+cB+1,sB.y);
  atomicAdd(base+cB+2,sB.z); atomicAdd(base+cB+3,sB.w);
  atomicAdd(base+2048+cA+0,qA.x); atomicAdd(base+2048+cA+1,qA.y);
  atomicAdd(base+2048+cA+2,qA.z); atomicAdd(base+2048+cA+3,qA.w);
  atomicAdd(base+2048+cB+0,qB.x); atomicAdd(base+2048+cB+1,qB.y);
  atomicAdd(base+2048+cB+2,qB.z); atomicAdd(base+2048+cB+3,qB.w);
  if (t == 0) atomicAdd(&counts[v], (float)m);
}

__global__ __launch_bounds__(256) void k2_finish_atomic(
    const float* __restrict__ acc, const float* __restrict__ counts,
    const float* __restrict__ cmean, const float* __restrict__ cstd,
    float* __restrict__ out) {
  const int c = blockIdx.x * 256 + threadIdx.x;
  float cnt[N_VIEWS];
  float nvalid = 0.f;
#pragma unroll
  for (int v = 0; v < N_VIEWS; ++v) {
    cnt[v] = counts[v];
    nvalid += (cnt[v] > 1.5f) ? 1.f : 0.f;
  }
  float mean[N_VIEWS], sd[N_VIEWS];
  float nm = 0.f, ns = 0.f;
#pragma unroll
  for (int v = 0; v < N_VIEWS; ++v) {
    float su = acc[v * TWO_C + c];
    float sq = acc[v * TWO_C + 2048 + c];
    float n = fmaxf(cnt[v], 1.f);
    float mu = su / n;
    float var = (sq - cnt[v] * mu * mu) / fmaxf(cnt[v] - 1.f, 1.f);
    float sdv = sqrtf(fmaxf(var, 0.f));
    mean[v] = mu;
    sd[v] = sdv;
    if (cnt[v] > 1.5f) { nm += mu; ns += sdv; }
  }
  nm /= nvalid;
  ns /= nvalid;
  const float cm = cmean[c] * (1.f - MOMENT_F) + nm * MOMENT_F;
  const float cs = cstd[c]  * (1.f - MOMENT_F) + ns * MOMENT_F;
  float contrib = 0.f;
#pragma unroll
  for (int v = 0; v < N_VIEWS; ++v) {
    if (cnt[v] > 1.5f) {
      float d1 = mean[v] - cm;
      float d2 = sd[v] - cs;
      contrib += d1 * d1 + d2 * d2;
    }
  }
  contrib /= (2.f * nvalid);
  for (int o = 32; o > 0; o >>= 1) contrib += __shfl_down(contrib, o, 64);
  __shared__ float wsum[4];
  const int lane = threadIdx.x & 63;
  const int w = threadIdx.x >> 6;
  if (lane == 0) wsum[w] = contrib;
  __syncthreads();
  if (threadIdx.x == 0)
    atomicAdd(out, wsum[0] + wsum[1] + wsum[2] + wsum[3]);
}

extern "C" void kernel_launch(void* const* d_in, const int* in_sizes, int n_in,
                              void* d_out, int out_size, void* d_ws, size_t ws_size,
                              hipStream_t stream) {
  const float* x     = (const float*)d_in[0];
  const float* cmean = (const float*)d_in[1];
  const float* cstd  = (const float*)d_in[2];
  const int*   views = (const int*)d_in[3];
  float* out = (float*)d_out;

  float* partCnt = (float*)d_ws;
  float* cnt2    = (float*)((char*)d_ws + 4096);
  float* part    = (float*)((char*)d_ws + 8192);
  float* acc2    = part + (size_t)SEGS * N_VIEWS * TWO_C;
  const size_t need = 8192 +
      ((size_t)SEGS * N_VIEWS * TWO_C + (size_t)NCHUNK * N_VIEWS * TWO_C) *
          sizeof(float);  // ~13.4 MB

  const int L = N_ROWS / SEGS;  // 128
  if (ws_size >= need) {
    // 3-node graph: no memsets, no global atomics anywhere.
    k1_segstats<<<N_VIEWS * SEGS, 256, 0, stream>>>(x, views, part, partCnt, L);
    k1b_reduce<<<NCHUNK * N_VIEWS * 1024 / 256, 256, 0, stream>>>(
        (const float4*)part, (float4*)acc2, partCnt, cnt2);
    k2_finish<<<1, 1024, 0, stream>>>(acc2, cnt2, cmean, cstd, out, out_size);
  } else {
    float* counts = (float*)d_ws;
    float* acc    = (float*)((char*)d_ws + 256);
    hipMemsetAsync(d_ws, 0, 256 + (size_t)N_VIEWS * TWO_C * sizeof(float), stream);
    hipMemsetAsync(d_out, 0, (size_t)out_size * sizeof(float), stream);
    k1_segstats_atomic<<<N_VIEWS * SEGS, 256, 0, stream>>>(x, views, acc, counts, L);
    k2_finish_atomic<<<C_COLS / 256, 256, 0, stream>>>(acc, counts, cmean, cstd, out);
  }
}